// Round 20
// baseline (22859.137 us; speedup 1.0000x reference)
//
#include <hip/hip_runtime.h>
#include <hip/hip_bf16.h>
#include <cfloat>

// FPS matching the np reference bit-exactly (R7: PASS, absmax 0).
// FROZEN per-point arithmetic: dx=px-cx; y2=dy*dy; inner=fma(dx,dx,y2);
// d=fma(dz,dz,inner); nd=fminf(dist,d); winner=(max value, smallest index).
// R20: single-block/batch structures all converge ~3.3k cy/step (one CU
// streams 192KB/step; 224 CUs idle). Split each batch across 8 blocks
// (256 blocks = 1/CU, coords 24KB/block = L1-resident), sync the 8 blocks
// per step via agent-scope atomics (parity-double-buffered cand/seq message
// passing; max skew 2 => no overwrite-before-read). Cooperative launch
// guarantees co-residency; seq zeroed per call via hipMemsetAsync.

#define FPS_THREADS 512
#define PARTS 8
#define PPT 4   // points/thread = 16384 / PARTS / FPS_THREADS

typedef unsigned long long u64;

template <int CTRL>
__device__ __forceinline__ float dpp_maxf(float v) {
  int iv = __float_as_int(v);
  int sh = __builtin_amdgcn_update_dpp(iv, iv, CTRL, 0xF, 0xF, false);
  return fmaxf(v, __int_as_float(sh));
}
template <int CTRL>
__device__ __forceinline__ unsigned dpp_maxu(unsigned v) {
  int sh = __builtin_amdgcn_update_dpp((int)v, (int)v, CTRL, 0xF, 0xF, false);
  return ((unsigned)sh > v) ? (unsigned)sh : v;
}
__device__ __forceinline__ float wave_maxf(float v) {
  v = dpp_maxf<0xB1>(v); v = dpp_maxf<0x4E>(v); v = dpp_maxf<0x141>(v);
  v = dpp_maxf<0x140>(v); v = dpp_maxf<0x142>(v); v = dpp_maxf<0x143>(v);
  return __int_as_float(__builtin_amdgcn_readlane(__float_as_int(v), 63));
}
__device__ __forceinline__ unsigned wave_maxu(unsigned v) {
  v = dpp_maxu<0xB1>(v); v = dpp_maxu<0x4E>(v); v = dpp_maxu<0x141>(v);
  v = dpp_maxu<0x140>(v); v = dpp_maxu<0x142>(v); v = dpp_maxu<0x143>(v);
  return (unsigned)__builtin_amdgcn_readlane((int)v, 63);
}

__global__ __launch_bounds__(FPS_THREADS) void transpose_kernel(
    const float* __restrict__ xyz, float2* __restrict__ xyp,
    float* __restrict__ zp, int N) {
  const int b = blockIdx.x;
  const int t = threadIdx.x;
  const float* xb = xyz + (size_t)b * N * 3;
  float2* xyb = xyp + (size_t)b * N;
  float* zb = zp + (size_t)b * N;
#pragma unroll
  for (int k = 0; k < 32; ++k) {
    int p = k * FPS_THREADS + t;
    xyb[p] = make_float2(xb[(size_t)p * 3 + 0], xb[(size_t)p * 3 + 1]);
    zb[p] = xb[(size_t)p * 3 + 2];
  }
}

__global__ __launch_bounds__(FPS_THREADS)
void fps_kernel(const float2* __restrict__ xyp, const float* __restrict__ zp,
                int* __restrict__ out_idx, u64* __restrict__ candbuf,
                unsigned* __restrict__ seqbuf, int N, int S) {
#pragma clang fp contract(off)
  const int b = blockIdx.x >> 3;
  const int part = blockIdx.x & 7;
  const int t = threadIdx.x;
  const float2* xyb = xyp + (size_t)b * N;
  const float* zb = zp + (size_t)b * N;
  u64* cb = candbuf + (size_t)b * 16;        // [2][8] parity slots
  unsigned* sb = seqbuf + (size_t)b * 16;    // [2][8] parity slots

  const int base = part * (N / PARTS);
  float px[PPT], py[PPT], pz[PPT], ds[PPT];
#pragma unroll
  for (int k = 0; k < PPT; ++k) {
    int p = base + k * FPS_THREADS + t;
    float2 xy = xyb[p];
    px[k] = xy.x; py[k] = xy.y; pz[k] = zb[p];
    ds[k] = FLT_MAX;
  }

  __shared__ u64 s_k[FPS_THREADS / 64];
  __shared__ int s_far;
  const int wave = t >> 6;
  const int lane = t & 63;
  int farthest = 0;

  for (int s = 0; s < S; ++s) {
    if (part == 0 && t == 0) out_idx[(size_t)b * S + s] = farthest;

    int f = __builtin_amdgcn_readfirstlane(farthest);
    float2 cxy = xyb[f];
    float cz = zb[f];
    float cx = cxy.x, cy = cxy.y;

    float bestv = -1.0f;
    int bestk = 0;
    // FROZEN reference arithmetic; k ascending => first occurrence
#pragma unroll
    for (int k = 0; k < PPT; ++k) {
      float dx = px[k] - cx;
      float dy = py[k] - cy;
      float dz = pz[k] - cz;
      float y2 = dy * dy;
      float inner = __builtin_fmaf(dx, dx, y2);
      float dd = __builtin_fmaf(dz, dz, inner);
      float nd = fminf(ds[k], dd);
      ds[k] = nd;
      if (nd > bestv) { bestv = nd; bestk = k; }
    }
    unsigned bestinv = 0xFFFFFFFFu - (unsigned)(base + bestk * FPS_THREADS + t);

    // wave reduce via DPP; dist >= 0 => u64 key max == (value, min orig idx)
    float wmax = wave_maxf(bestv);
    unsigned cand = (bestv == wmax) ? bestinv : 0u;
    unsigned winv = wave_maxu(cand);
    if (lane == 0)
      s_k[wave] = ((u64)__float_as_uint(wmax) << 32) | (u64)winv;
    __syncthreads();

    if (wave == 0) {
      u64 kk = s_k[lane & 7];
#pragma unroll
      for (int off = 1; off < 8; off <<= 1) {
        u64 ok = __shfl_xor(kk, off, 64);
        if (ok > kk) kk = ok;
      }
      const int par = s & 1;
      if (lane == 0) {
        __hip_atomic_store(&cb[par * 8 + part], kk,
                           __ATOMIC_RELAXED, __HIP_MEMORY_SCOPE_AGENT);
        __hip_atomic_store(&sb[par * 8 + part], (unsigned)(s + 1),
                           __ATOMIC_RELEASE, __HIP_MEMORY_SCOPE_AGENT);
      }
      u64 gk = 0;
      if (lane < 8) {
        while (__hip_atomic_load(&sb[par * 8 + lane], __ATOMIC_ACQUIRE,
                                 __HIP_MEMORY_SCOPE_AGENT) < (unsigned)(s + 1)) {}
        gk = __hip_atomic_load(&cb[par * 8 + lane], __ATOMIC_RELAXED,
                               __HIP_MEMORY_SCOPE_AGENT);
      }
#pragma unroll
      for (int off = 1; off < 8; off <<= 1) {
        u64 ok = __shfl_xor(gk, off, 64);
        if (ok > gk) gk = ok;
      }
      if (lane == 0)
        s_far = (int)(0xFFFFFFFFu - (unsigned)(gk & 0xFFFFFFFFu));
    }
    __syncthreads();
    farthest = s_far;
  }
}

// Gather: out = [ xyz[b][idx[b][s]][c] (B*S*3) , feat[b][idx[b][s]][:] (B*S*C) ]
__global__ void gather_kernel(const float* __restrict__ xyz,
                              const float* __restrict__ feat,
                              const int* __restrict__ idx,
                              float* __restrict__ out,
                              int B, int N, int S, int C) {
  const int c4pr = C >> 2;
  const int nf4 = B * S * c4pr;
  int tid = blockIdx.x * blockDim.x + threadIdx.x;
  if (tid < nf4) {
    int c4 = tid % c4pr;
    int bs = tid / c4pr;
    int s = bs % S, b = bs / S;
    int p = idx[b * S + s];
    const float4* src = (const float4*)(feat + ((size_t)b * N + p) * C);
    float4* dst = (float4*)(out + (size_t)B * S * 3 + ((size_t)bs) * C);
    dst[c4] = src[c4];
  } else {
    int t2 = tid - nf4;
    int nxyz = B * S * 3;
    if (t2 < nxyz) {
      int c = t2 % 3;
      int bs = t2 / 3;
      int s = bs % S, b = bs / S;
      int p = idx[b * S + s];
      out[t2] = xyz[((size_t)b * N + p) * 3 + c];
    }
  }
}

extern "C" void kernel_launch(void* const* d_in, const int* in_sizes, int n_in,
                              void* d_out, int out_size, void* d_ws, size_t ws_size,
                              hipStream_t stream) {
  const float* xyz = (const float*)d_in[0];
  const float* feat = (const float*)d_in[1];
  float* out = (float*)d_out;

  const int B = 32;
  const int N = in_sizes[0] / (B * 3);        // 16384
  const int C = in_sizes[1] / (B * N);        // 128
  const int S = N / 4;                        // 4096

  // ws layout: idx 512KB | xy 4MB | z 2MB | cand 4KB | seq 2KB
  int* d_idx = (int*)d_ws;
  float2* d_xy = (float2*)((char*)d_ws + (size_t)B * S * sizeof(int));
  float* d_z = (float*)((char*)d_xy + (size_t)B * N * sizeof(float2));
  u64* d_cand = (u64*)((char*)d_z + (size_t)B * N * sizeof(float));
  unsigned* d_seq = (unsigned*)((char*)d_cand + (size_t)B * 16 * sizeof(u64));

  hipMemsetAsync(d_seq, 0, (size_t)B * 16 * sizeof(unsigned), stream);
  transpose_kernel<<<B, FPS_THREADS, 0, stream>>>(xyz, d_xy, d_z, N);

  int* idxp = d_idx; const float2* xyp = d_xy; const float* zp = d_z;
  u64* candp = d_cand; unsigned* seqp = d_seq; int n = N, ss = S;
  void* args[] = {(void*)&xyp, (void*)&zp, (void*)&idxp,
                  (void*)&candp, (void*)&seqp, (void*)&n, (void*)&ss};
  hipLaunchCooperativeKernel((const void*)fps_kernel,
                             dim3(B * PARTS), dim3(FPS_THREADS),
                             args, 0, stream);

  int total = B * S * (C >> 2) + B * S * 3;
  int blocks = (total + 255) / 256;
  gather_kernel<<<blocks, 256, 0, stream>>>(xyz, feat, d_idx, out, B, N, S, C);
}

// Round 21
// 9988.010 us; speedup vs baseline: 2.2887x; 2.2887x over previous
//
#include <hip/hip_runtime.h>
#include <hip/hip_bf16.h>
#include <cfloat>

// FPS matching the np reference bit-exactly (R7: PASS, absmax 0).
// FROZEN per-point arithmetic: dx=px-cx; y2=dy*dy; inner=fma(dx,dx,y2);
// d=fma(dz,dz,inner); nd=fminf(dist,d); winner=(max value, smallest index).
// R21: exact bucket-pruned FPS. 512 grid cells/batch; skip cell if
// d_lower(c, cellbox) > cell max dist (then fminf is a no-op for every
// point => dist and cell max stay exact by induction; step 0 scans all).
// Winner via u64 (distbits|invidx) keys == reference first-occurrence
// argmax, scan-order independent. Margins (pad 1e-4*range, bound*0.999)
// cover all fp32 rounding of the bound vs the frozen chain.

typedef unsigned long long u64;
#define CELLS 512
#define PREP_T 512
#define FPS_T 1024

__global__ __launch_bounds__(PREP_T) void prep_kernel(
    const float* __restrict__ xyz, float4* __restrict__ rp,
    int* __restrict__ cstart, int* __restrict__ ccnt,
    float* __restrict__ bbox, int N) {
  const int b = blockIdx.x, t = threadIdx.x;
  const float* xb = xyz + (size_t)b * N * 3;
  __shared__ int s_cnt[CELLS], s_start[CELLS], s_off[CELLS];
  __shared__ float s_red[8][6];
  __shared__ float s_bb[6];
  const int PPT = N / PREP_T;
  const int wave = t >> 6, lane = t & 63;

  float mnx = FLT_MAX, mny = FLT_MAX, mnz = FLT_MAX;
  float mxx = -FLT_MAX, mxy = -FLT_MAX, mxz = -FLT_MAX;
  for (int k = 0; k < PPT; ++k) {
    int p = k * PREP_T + t;
    float x = xb[(size_t)p * 3], y = xb[(size_t)p * 3 + 1], z = xb[(size_t)p * 3 + 2];
    mnx = fminf(mnx, x); mny = fminf(mny, y); mnz = fminf(mnz, z);
    mxx = fmaxf(mxx, x); mxy = fmaxf(mxy, y); mxz = fmaxf(mxz, z);
  }
  for (int off = 32; off > 0; off >>= 1) {
    mnx = fminf(mnx, __shfl_xor(mnx, off, 64));
    mny = fminf(mny, __shfl_xor(mny, off, 64));
    mnz = fminf(mnz, __shfl_xor(mnz, off, 64));
    mxx = fmaxf(mxx, __shfl_xor(mxx, off, 64));
    mxy = fmaxf(mxy, __shfl_xor(mxy, off, 64));
    mxz = fmaxf(mxz, __shfl_xor(mxz, off, 64));
  }
  if (lane == 0) {
    s_red[wave][0] = mnx; s_red[wave][1] = mny; s_red[wave][2] = mnz;
    s_red[wave][3] = mxx; s_red[wave][4] = mxy; s_red[wave][5] = mxz;
  }
  __syncthreads();
  if (t == 0) {
    float a = s_red[0][0], bq = s_red[0][1], c = s_red[0][2];
    float d = s_red[0][3], e = s_red[0][4], g = s_red[0][5];
    for (int w = 1; w < 8; ++w) {
      a = fminf(a, s_red[w][0]); bq = fminf(bq, s_red[w][1]); c = fminf(c, s_red[w][2]);
      d = fmaxf(d, s_red[w][3]); e = fmaxf(e, s_red[w][4]); g = fmaxf(g, s_red[w][5]);
    }
    s_bb[0] = a; s_bb[1] = bq; s_bb[2] = c; s_bb[3] = d; s_bb[4] = e; s_bb[5] = g;
    for (int i = 0; i < 6; ++i) bbox[b * 6 + i] = s_bb[i];
  }
  if (t < CELLS) s_cnt[t] = 0;
  __syncthreads();

  float lox = s_bb[0], loy = s_bb[1], loz = s_bb[2];
  float rx = s_bb[3] - lox, ry = s_bb[4] - loy, rz = s_bb[5] - loz;
  float sx = (rx > 0.f) ? 8.f / rx : 0.f;
  float sy = (ry > 0.f) ? 8.f / ry : 0.f;
  float sz = (rz > 0.f) ? 8.f / rz : 0.f;

#define CIDX(v, lo, sc) ({ int cc_ = (int)(((v) - (lo)) * (sc)); cc_ < 0 ? 0 : (cc_ > 7 ? 7 : cc_); })

  for (int k = 0; k < PPT; ++k) {
    int p = k * PREP_T + t;
    float x = xb[(size_t)p * 3], y = xb[(size_t)p * 3 + 1], z = xb[(size_t)p * 3 + 2];
    int cid = (CIDX(x, lox, sx) << 6) | (CIDX(y, loy, sy) << 3) | CIDX(z, loz, sz);
    atomicAdd(&s_cnt[cid], 1);
  }
  __syncthreads();
  if (t < CELLS) s_start[t] = s_cnt[t];
  __syncthreads();
  for (int off = 1; off < CELLS; off <<= 1) {
    int add = 0;
    if (t < CELLS && t >= off) add = s_start[t - off];
    __syncthreads();
    if (t < CELLS) s_start[t] += add;
    __syncthreads();
  }
  if (t < CELLS) { s_start[t] -= s_cnt[t]; s_off[t] = 0; }
  __syncthreads();

  for (int k = 0; k < PPT; ++k) {
    int p = k * PREP_T + t;
    float x = xb[(size_t)p * 3], y = xb[(size_t)p * 3 + 1], z = xb[(size_t)p * 3 + 2];
    int cid = (CIDX(x, lox, sx) << 6) | (CIDX(y, loy, sy) << 3) | CIDX(z, loz, sz);
    int pos = s_start[cid] + atomicAdd(&s_off[cid], 1);
    rp[(size_t)b * N + pos] =
        make_float4(x, y, z, __uint_as_float(0xFFFFFFFFu - (unsigned)p));
  }
  if (t < CELLS) {
    cstart[b * CELLS + t] = s_start[t];
    ccnt[b * CELLS + t] = s_cnt[t];
  }
}

__global__ __launch_bounds__(FPS_T)
void fps_kernel(const float* __restrict__ xyz, const float4* __restrict__ rp,
                const int* __restrict__ cstart, const int* __restrict__ ccnt,
                const float* __restrict__ bbox, int* __restrict__ out_idx,
                int N, int S) {
#pragma clang fp contract(off)
  const int b = blockIdx.x, t = threadIdx.x;
  const int wave = t >> 6, lane = t & 63;
  const float* xb = xyz + (size_t)b * N * 3;
  const float4* rpb = rp + (size_t)b * N;

  __shared__ float s_dist[16384];     // 64 KB
  __shared__ u64 s_key[CELLS];        // 4 KB
  __shared__ int s_cs[CELLS], s_cc[CELLS], s_wl[CELLS];
  __shared__ int s_nw[2];
  __shared__ u64 s_part[16];
  __shared__ int s_far;
  __shared__ float s_bb[6];

  if (t < 6) s_bb[t] = bbox[b * 6 + t];
  if (t < CELLS) {
    s_cs[t] = cstart[b * CELLS + t];
    s_cc[t] = ccnt[b * CELLS + t];
    s_key[t] = (s_cc[t] > 0) ? (((u64)0x7F7FFFFFu) << 32) : 0ull;  // FLT_MAX bits
  }
  if (t < 2) s_nw[t] = 0;
  for (int i = t; i < N; i += FPS_T) s_dist[i] = FLT_MAX;
  __syncthreads();

  const float lox = s_bb[0], loy = s_bb[1], loz = s_bb[2];
  const float rx = s_bb[3] - lox, ry = s_bb[4] - loy, rz = s_bb[5] - loz;
  const float csx = rx * 0.125f, csy = ry * 0.125f, csz = rz * 0.125f;
  const float pad = 1e-4f * fmaxf(rx, fmaxf(ry, rz));

  int farthest = 0;
  for (int s = 0; s < S; ++s) {
    if (t == 0) out_idx[(size_t)b * S + s] = farthest;
    int f = __builtin_amdgcn_readfirstlane(farthest);
    float cx = xb[(size_t)f * 3], cy = xb[(size_t)f * 3 + 1], cz = xb[(size_t)f * 3 + 2];
    const int par = s & 1;

    // check phase: thread t = cell t
    if (t < CELLS && s_cc[t] > 0) {
      float maxv = __uint_as_float((unsigned)(s_key[t] >> 32));
      int ci = (t >> 6) & 7, cj = (t >> 3) & 7, ck = t & 7;
      float cl = lox + ci * csx - pad, ch = lox + (ci + 1) * csx + pad;
      float gx = fmaxf(0.f, fmaxf(cl - cx, cx - ch));
      cl = loy + cj * csy - pad; ch = loy + (cj + 1) * csy + pad;
      float gy = fmaxf(0.f, fmaxf(cl - cy, cy - ch));
      cl = loz + ck * csz - pad; ch = loz + (ck + 1) * csz + pad;
      float gz = fmaxf(0.f, fmaxf(cl - cz, cz - ch));
      float bound = gx * gx + gy * gy + gz * gz;
      if (bound * 0.999f <= maxv) {
        int pos = atomicAdd(&s_nw[par], 1);
        s_wl[pos] = t;
      }
    }
    __syncthreads();  // B1

    // scan phase: waves consume worklist
    int nw = s_nw[par];
    for (int w = wave; w < nw; w += FPS_T / 64) {
      int cell = s_wl[w];
      int st = s_cs[cell], cnt = s_cc[cell];
      u64 ck = 0;
      for (int i = lane; i < cnt; i += 64) {
        int pos = st + i;
        float4 q = rpb[pos];
        // FROZEN reference arithmetic:
        float dx = q.x - cx, dy = q.y - cy, dz = q.z - cz;
        float y2 = dy * dy;
        float inner = __builtin_fmaf(dx, dx, y2);
        float dd = __builtin_fmaf(dz, dz, inner);
        float nd = fminf(s_dist[pos], dd);
        s_dist[pos] = nd;
        u64 key = ((u64)__float_as_uint(nd) << 32) | (u64)__float_as_uint(q.w);
        if (key > ck) ck = key;
      }
#pragma unroll
      for (int off = 32; off > 0; off >>= 1) {
        u64 ok = __shfl_xor(ck, off, 64);
        if (ok > ck) ck = ok;
      }
      if (lane == 0) s_key[cell] = ck;
    }
    if (t == 0) s_nw[par ^ 1] = 0;
    __syncthreads();  // B2

    // global argmax over 512 cell keys
    u64 gk = (t < CELLS) ? s_key[t] : 0;
#pragma unroll
    for (int off = 32; off > 0; off >>= 1) {
      u64 ok = __shfl_xor(gk, off, 64);
      if (ok > gk) gk = ok;
    }
    if (lane == 0) s_part[wave] = gk;
    __syncthreads();  // B3
    if (t == 0) {
      u64 m = s_part[0];
      for (int w = 1; w < 8; ++w) if (s_part[w] > m) m = s_part[w];
      s_far = (int)(0xFFFFFFFFu - (unsigned)(m & 0xFFFFFFFFu));
    }
    __syncthreads();  // B4
    farthest = s_far;
  }
}

// Gather: out = [ xyz[b][idx[b][s]][c] (B*S*3) , feat[b][idx[b][s]][:] (B*S*C) ]
__global__ void gather_kernel(const float* __restrict__ xyz,
                              const float* __restrict__ feat,
                              const int* __restrict__ idx,
                              float* __restrict__ out,
                              int B, int N, int S, int C) {
  const int c4pr = C >> 2;
  const int nf4 = B * S * c4pr;
  int tid = blockIdx.x * blockDim.x + threadIdx.x;
  if (tid < nf4) {
    int c4 = tid % c4pr;
    int bs = tid / c4pr;
    int s = bs % S, b = bs / S;
    int p = idx[b * S + s];
    const float4* src = (const float4*)(feat + ((size_t)b * N + p) * C);
    float4* dst = (float4*)(out + (size_t)B * S * 3 + ((size_t)bs) * C);
    dst[c4] = src[c4];
  } else {
    int t2 = tid - nf4;
    int nxyz = B * S * 3;
    if (t2 < nxyz) {
      int c = t2 % 3;
      int bs = t2 / 3;
      int s = bs % S, b = bs / S;
      int p = idx[b * S + s];
      out[t2] = xyz[((size_t)b * N + p) * 3 + c];
    }
  }
}

extern "C" void kernel_launch(void* const* d_in, const int* in_sizes, int n_in,
                              void* d_out, int out_size, void* d_ws, size_t ws_size,
                              hipStream_t stream) {
  const float* xyz = (const float*)d_in[0];
  const float* feat = (const float*)d_in[1];
  float* out = (float*)d_out;

  const int B = 32;
  const int N = in_sizes[0] / (B * 3);        // 16384
  const int C = in_sizes[1] / (B * N);        // 128
  const int S = N / 4;                        // 4096

  // ws: idx 512KB | rp 8MB | cstart 64KB | ccnt 64KB | bbox 768B
  int* d_idx = (int*)d_ws;
  float4* d_rp = (float4*)((char*)d_ws + (size_t)B * S * sizeof(int));
  int* d_cs = (int*)((char*)d_rp + (size_t)B * N * sizeof(float4));
  int* d_cc = (int*)((char*)d_cs + (size_t)B * CELLS * sizeof(int));
  float* d_bb = (float*)((char*)d_cc + (size_t)B * CELLS * sizeof(int));

  prep_kernel<<<B, PREP_T, 0, stream>>>(xyz, d_rp, d_cs, d_cc, d_bb, N);
  fps_kernel<<<B, FPS_T, 0, stream>>>(xyz, d_rp, d_cs, d_cc, d_bb, d_idx, N, S);

  int total = B * S * (C >> 2) + B * S * 3;
  int blocks = (total + 255) / 256;
  gather_kernel<<<blocks, 256, 0, stream>>>(xyz, feat, d_idx, out, B, N, S, C);
}